// Round 4
// baseline (203.207 us; speedup 1.0000x reference)
//
#include <hip/hip_runtime.h>

// ---------------------------------------------------------------------------
// JobSchedulerGNN round 4: un-fuse aggregate (latency-bound, needs occupancy)
// from GEMM. CSR rows padded to 4 so index loads are int4; gather unrolled
// 8/4/1 for up to 8 outstanding row loads per lane. GEMM = register-only dual
// MFMA (64-row tiles); layer-2 GEMM fuses both heads in the epilogue.
// 9 dispatches, no memset in graph.
// ---------------------------------------------------------------------------

#define D 128

typedef unsigned short ushort8 __attribute__((ext_vector_type(8)));
typedef __bf16 bf16x8 __attribute__((ext_vector_type(8)));
typedef float f32x4 __attribute__((ext_vector_type(4)));

__device__ inline unsigned short f2bf(float f) {
  unsigned u = __float_as_uint(f);
  u += 0x7FFFu + ((u >> 16) & 1u);  // RNE
  return (unsigned short)(u >> 16);
}
__device__ inline float bf2f(unsigned short h) {
  return __uint_as_float((unsigned)h << 16);
}

// ---- prep: convert_x | convert_w | zero-deg, selected by blockIdx ----------
__global__ __launch_bounds__(256) void k_prep(
    const float* __restrict__ x, unsigned short* __restrict__ xb, int total8,
    const float* __restrict__ s0, const float* __restrict__ s1,
    const float* __restrict__ s2, const float* __restrict__ s3,
    unsigned short* __restrict__ d0, unsigned short* __restrict__ d1,
    unsigned short* __restrict__ d2, unsigned short* __restrict__ d3,
    int* __restrict__ deg, int n, int xB) {
  int b = blockIdx.x;
  int t = threadIdx.x;
  if (b < xB) {                      // x -> bf16, 8 elems/thread
    int i = b * 256 + t;
    if (i >= total8) return;
    const float4* p = (const float4*)(x + (size_t)i * 8);
    float4 v0 = p[0], v1 = p[1];
    ushort8 o;
    o[0] = f2bf(v0.x); o[1] = f2bf(v0.y); o[2] = f2bf(v0.z); o[3] = f2bf(v0.w);
    o[4] = f2bf(v1.x); o[5] = f2bf(v1.y); o[6] = f2bf(v1.z); o[7] = f2bf(v1.w);
    *(ushort8*)(xb + (size_t)i * 8) = o;
  } else if (b < xB + 256) {         // 4x [128][128] f32 -> bf16 transposed
    int idx = (b - xB) * 256 + t;
    int mat = idx >> 14;
    int rem = idx & 16383;
    int k = rem >> 7, nn = rem & 127;
    const float* s = (mat == 0) ? s0 : (mat == 1) ? s1 : (mat == 2) ? s2 : s3;
    unsigned short* d = (mat == 0) ? d0 : (mat == 1) ? d1 : (mat == 2) ? d2 : d3;
    d[nn * 128 + k] = f2bf(s[k * 128 + nn]);
  } else {                           // zero deg
    int i0 = (b - xB - 256) * 1024 + t * 4;
    #pragma unroll
    for (int i = 0; i < 4; i++)
      if (i0 + i < n) deg[i0 + i] = 0;
  }
}

// ---- CSR build (row starts padded to 4 ints) -------------------------------
__global__ __launch_bounds__(256) void k_count(const int* __restrict__ dst,
                                               int* __restrict__ deg, int E) {
  int e = blockIdx.x * blockDim.x + threadIdx.x;
  if (e < E) atomicAdd(&deg[dst[e]], 1);
}

// exclusive scan of PADDED degrees ((d+3)&~3) -> cursor; block totals -> part
__global__ __launch_bounds__(256) void k_scan1(const int* __restrict__ deg,
                                               int* __restrict__ cursor,
                                               int* __restrict__ part, int n) {
  __shared__ int sd[256];
  int t = threadIdx.x;
  int i0 = blockIdx.x * 1024 + t * 4;
  int v0 = (i0 + 0 < n) ? ((deg[i0 + 0] + 3) & ~3) : 0;
  int v1 = (i0 + 1 < n) ? ((deg[i0 + 1] + 3) & ~3) : 0;
  int v2 = (i0 + 2 < n) ? ((deg[i0 + 2] + 3) & ~3) : 0;
  int v3 = (i0 + 3 < n) ? ((deg[i0 + 3] + 3) & ~3) : 0;
  int s = v0 + v1 + v2 + v3;
  int incl = s;
  sd[t] = incl;
  __syncthreads();
  #pragma unroll
  for (int off = 1; off < 256; off <<= 1) {
    int add = (t >= off) ? sd[t - off] : 0;
    __syncthreads();
    incl += add;
    sd[t] = incl;
    __syncthreads();
  }
  if (t == 255) part[blockIdx.x] = incl;
  int run = incl - s;
  if (i0 + 0 < n) cursor[i0 + 0] = run; run += v0;
  if (i0 + 1 < n) cursor[i0 + 1] = run; run += v1;
  if (i0 + 2 < n) cursor[i0 + 2] = run; run += v2;
  if (i0 + 3 < n) cursor[i0 + 3] = run;
}

// adds prefix-sum of part[0..blockIdx) computed in-kernel (wave reduce).
__global__ __launch_bounds__(256) void k_scan3(int* __restrict__ cursor,
                                               const int* __restrict__ part,
                                               int n) {
  __shared__ int sadd;
  int t = threadIdx.x;
  if (t < 64) {
    int s = 0;
    for (int i = t; i < blockIdx.x; i += 64) s += part[i];
    #pragma unroll
    for (int off = 32; off > 0; off >>= 1) s += __shfl_down(s, off);
    if (t == 0) sadd = s;
  }
  __syncthreads();
  int add = sadd;
  int i0 = blockIdx.x * 1024 + t * 4;
  #pragma unroll
  for (int i = 0; i < 4; i++)
    if (i0 + i < n) cursor[i0 + i] += add;
}

// pos = bump(cursor[dst]); csr[pos] = src. After: cursor[d] = padded_start+cnt.
__global__ __launch_bounds__(256) void k_fill(const int* __restrict__ ei,
                                              int* __restrict__ cursor,
                                              int* __restrict__ csr, int E) {
  int e = blockIdx.x * blockDim.x + threadIdx.x;
  if (e < E) {
    int s = ei[e];
    int d = ei[E + e];
    int pos = atomicAdd(&cursor[d], 1);
    csr[pos] = s;
  }
}

// ---- aggregate: 16 lanes/node, int4 index loads, 8-deep row pipelining -----
__global__ __launch_bounds__(256) void k_aggregate(
    const unsigned short* __restrict__ H, const int* __restrict__ csr,
    const int* __restrict__ cursor, const int* __restrict__ deg,
    unsigned short* __restrict__ out, int n) {
  int t = threadIdx.x;
  int node = blockIdx.x * 16 + (t >> 4);
  if (node >= n) return;
  int f = (t & 15) * 8;
  int cnt = deg[node];
  int start = cursor[node] - cnt;  // padded start, start % 4 == 0
  float acc[8] = {0.f, 0.f, 0.f, 0.f, 0.f, 0.f, 0.f, 0.f};
  const unsigned short* Hf = H + f;
  int j = 0;
  for (; j + 8 <= cnt; j += 8) {
    int4 i0 = *(const int4*)&csr[start + j];
    int4 i1 = *(const int4*)&csr[start + j + 4];
    ushort8 h0 = *(const ushort8*)&Hf[(size_t)i0.x * D];
    ushort8 h1 = *(const ushort8*)&Hf[(size_t)i0.y * D];
    ushort8 h2 = *(const ushort8*)&Hf[(size_t)i0.z * D];
    ushort8 h3 = *(const ushort8*)&Hf[(size_t)i0.w * D];
    ushort8 h4 = *(const ushort8*)&Hf[(size_t)i1.x * D];
    ushort8 h5 = *(const ushort8*)&Hf[(size_t)i1.y * D];
    ushort8 h6 = *(const ushort8*)&Hf[(size_t)i1.z * D];
    ushort8 h7 = *(const ushort8*)&Hf[(size_t)i1.w * D];
    #pragma unroll
    for (int e = 0; e < 8; e++)
      acc[e] += ((bf2f(h0[e]) + bf2f(h1[e])) + (bf2f(h2[e]) + bf2f(h3[e]))) +
                ((bf2f(h4[e]) + bf2f(h5[e])) + (bf2f(h6[e]) + bf2f(h7[e])));
  }
  if (j + 4 <= cnt) {
    int4 i0 = *(const int4*)&csr[start + j];
    ushort8 h0 = *(const ushort8*)&Hf[(size_t)i0.x * D];
    ushort8 h1 = *(const ushort8*)&Hf[(size_t)i0.y * D];
    ushort8 h2 = *(const ushort8*)&Hf[(size_t)i0.z * D];
    ushort8 h3 = *(const ushort8*)&Hf[(size_t)i0.w * D];
    #pragma unroll
    for (int e = 0; e < 8; e++)
      acc[e] += (bf2f(h0[e]) + bf2f(h1[e])) + (bf2f(h2[e]) + bf2f(h3[e]));
    j += 4;
  }
  for (; j < cnt; j++) {
    int a = csr[start + j];
    ushort8 ha = *(const ushort8*)&Hf[(size_t)a * D];
    #pragma unroll
    for (int e = 0; e < 8; e++) acc[e] += bf2f(ha[e]);
  }
  ushort8 o;
  #pragma unroll
  for (int e = 0; e < 8; e++) o[e] = f2bf(acc[e]);
  *(ushort8*)&out[(size_t)node * D + f] = o;
}

// ---- dual GEMM via MFMA, 64-row tile, register-only ------------------------
// C = relu(A1@W1 + A2@W2 + bias). Wave w owns rows blk*64+w*16 (M_rep=1),
// all 128 cols (nr=0..7). HEADS: fold task_allocation/task_order epilogue.
// C/D layout (HW-verified): col=lane&15, row=(lane>>4)*4+reg.
template <bool HEADS>
__global__ __launch_bounds__(256) void k_gemm(
    const unsigned short* __restrict__ A1, const unsigned short* __restrict__ B1T,
    const unsigned short* __restrict__ A2, const unsigned short* __restrict__ B2T,
    const float* __restrict__ bias, unsigned short* __restrict__ Cout,
    const float* __restrict__ Wa, const float* __restrict__ ba,
    const float* __restrict__ Wo, const float* __restrict__ bo,
    float* __restrict__ out, int n) {
  const int tid = threadIdx.x;
  const int w = tid >> 6;
  const int l = tid & 63;
  const int lr = l & 15;
  const int kg = l >> 4;
  const int grow = blockIdx.x * 64 + w * 16 + lr;  // A row for this lane

  f32x4 acc[8];
  f32x4 zf = {0.f, 0.f, 0.f, 0.f};
  #pragma unroll
  for (int nr = 0; nr < 8; nr++) acc[nr] = zf;

  #pragma unroll
  for (int pass = 0; pass < 2; pass++) {
    const unsigned short* A = pass ? A2 : A1;
    const unsigned short* BT = pass ? B2T : B1T;
    #pragma unroll
    for (int k0 = 0; k0 < 128; k0 += 32) {
      const int kb = k0 + kg * 8;
      uint4 av = make_uint4(0u, 0u, 0u, 0u);
      if (grow < n) av = *(const uint4*)&A[(size_t)grow * D + kb];
      bf16x8 a = __builtin_bit_cast(bf16x8, av);
      #pragma unroll
      for (int nr = 0; nr < 8; nr++) {
        uint4 v = *(const uint4*)&BT[(size_t)(nr * 16 + lr) * D + kb];
        acc[nr] = __builtin_amdgcn_mfma_f32_16x16x32_bf16(
            a, __builtin_bit_cast(bf16x8, v), acc[nr], 0, 0, 0);
      }
    }
  }

  float bcol[8];
  #pragma unroll
  for (int nr = 0; nr < 8; nr++) bcol[nr] = bias[nr * 16 + lr];

  if (!HEADS) {
    #pragma unroll
    for (int r = 0; r < 4; r++) {
      int row = blockIdx.x * 64 + w * 16 + kg * 4 + r;
      if (row < n) {
        #pragma unroll
        for (int nr = 0; nr < 8; nr++)
          Cout[(size_t)row * D + nr * 16 + lr] =
              f2bf(fmaxf(acc[nr][r] + bcol[nr], 0.f));
      }
    }
  } else {
    float pa0[4] = {0.f, 0.f, 0.f, 0.f};
    float pa1[4] = {0.f, 0.f, 0.f, 0.f};
    float po[4]  = {0.f, 0.f, 0.f, 0.f};
    #pragma unroll
    for (int nr = 0; nr < 8; nr++) {
      const int col = nr * 16 + lr;
      const float wa0 = Wa[col * 2 + 0];
      const float wa1 = Wa[col * 2 + 1];
      const float wo  = Wo[col];
      #pragma unroll
      for (int r = 0; r < 4; r++) {
        float hv = fmaxf(acc[nr][r] + bcol[nr], 0.f);
        pa0[r] += hv * wa0;
        pa1[r] += hv * wa1;
        po[r]  += hv * wo;
      }
    }
    #pragma unroll
    for (int off = 1; off < 16; off <<= 1) {
      #pragma unroll
      for (int r = 0; r < 4; r++) {
        pa0[r] += __shfl_xor(pa0[r], off);
        pa1[r] += __shfl_xor(pa1[r], off);
        po[r]  += __shfl_xor(po[r], off);
      }
    }
    if (lr == 0) {
      const float vba0 = ba[0], vba1 = ba[1], vbo = bo[0];
      #pragma unroll
      for (int r = 0; r < 4; r++) {
        int row = blockIdx.x * 64 + w * 16 + kg * 4 + r;
        if (row < n) {
          out[(size_t)row * 2 + 0] = pa0[r] + vba0;
          out[(size_t)row * 2 + 1] = pa1[r] + vba1;
          out[(size_t)2 * n + row] = po[r] + vbo;
        }
      }
    }
  }
}

// ---- launch -----------------------------------------------------------------
extern "C" void kernel_launch(void* const* d_in, const int* in_sizes, int n_in,
                              void* d_out, int out_size, void* d_ws, size_t ws_size,
                              hipStream_t stream) {
  const float* x       = (const float*)d_in[0];
  const int*   ei      = (const int*)d_in[1];
  const float* W1_rel  = (const float*)d_in[2];
  const float* b1      = (const float*)d_in[3];
  const float* W1_root = (const float*)d_in[4];
  const float* W2_rel  = (const float*)d_in[5];
  const float* b2      = (const float*)d_in[6];
  const float* W2_root = (const float*)d_in[7];
  const float* Wa      = (const float*)d_in[8];
  const float* ba      = (const float*)d_in[9];
  const float* Wo      = (const float*)d_in[10];
  const float* bo      = (const float*)d_in[11];
  float* out = (float*)d_out;

  const int N = in_sizes[0] / D;
  const int E = in_sizes[1] / 2;

  char* w = (char*)d_ws;
  unsigned short* xb   = (unsigned short*)w; w += (size_t)N * D * 2;
  unsigned short* aggb = (unsigned short*)w; w += (size_t)N * D * 2;
  unsigned short* h1b  = (unsigned short*)w; w += (size_t)N * D * 2;
  unsigned short* WT1r = (unsigned short*)w; w += 128 * 128 * 2;
  unsigned short* WT1x = (unsigned short*)w; w += 128 * 128 * 2;
  unsigned short* WT2r = (unsigned short*)w; w += 128 * 128 * 2;
  unsigned short* WT2x = (unsigned short*)w; w += 128 * 128 * 2;
  int* deg    = (int*)w; w += (size_t)N * 4;
  int* cursor = (int*)w; w += (size_t)N * 4;
  int* csr    = (int*)w; w += ((size_t)E + 3 * (size_t)N) * 4;  // padded rows
  int* part   = (int*)w; w += 64 * 4;

  const int nblk = (N + 1023) / 1024;
  const int xB = (N * 16 + 255) / 256;

  k_prep<<<xB + 256 + nblk, 256, 0, stream>>>(
      x, xb, N * 16, W1_rel, W1_root, W2_rel, W2_root,
      WT1r, WT1x, WT2r, WT2x, deg, N, xB);
  k_count<<<(E + 255) / 256, 256, 0, stream>>>(ei + E, deg, E);
  k_scan1<<<nblk, 256, 0, stream>>>(deg, cursor, part, N);
  k_scan3<<<nblk, 256, 0, stream>>>(cursor, part, N);
  k_fill<<<(E + 255) / 256, 256, 0, stream>>>(ei, cursor, csr, E);

  const int ablk = (N + 15) / 16;
  const int gblk = (N + 63) / 64;
  // layer 1: x -> h1
  k_aggregate<<<ablk, 256, 0, stream>>>(xb, csr, cursor, deg, aggb, N);
  k_gemm<false><<<gblk, 256, 0, stream>>>(
      aggb, WT1r, xb, WT1x, b1, h1b,
      nullptr, nullptr, nullptr, nullptr, nullptr, N);
  // layer 2 + heads: h1 -> out
  k_aggregate<<<ablk, 256, 0, stream>>>(h1b, csr, cursor, deg, aggb, N);
  k_gemm<true><<<gblk, 256, 0, stream>>>(
      aggb, WT2r, h1b, WT2x, b2, nullptr,
      Wa, ba, Wo, bo, out, N);
}